// Round 1
// baseline (908.158 us; speedup 1.0000x reference)
//
#include <hip/hip_runtime.h>

#define NLAYERS 13
#define BATCH 32
#define SEQ 128
#define HID 768
#define NU 32      // GRU units
#define GG 64      // 2*NU
#define TU 96      // 3*NU
#define ROWS 16    // rows per block in layer_front
#define BK 128     // k-tile
#define NROWS (BATCH * SEQ)  // 4096
#define LN_EPS 1e-3f

__device__ __forceinline__ float sigmoidf_(float a) {
    return 1.0f / (1.0f + __expf(-a));
}
__device__ __forceinline__ float tanhf_(float a) {
    float e = __expf(-2.0f * a);
    return (1.0f - e) / (1.0f + e);
}

// Fused: lin = xs@W_lin + b_lin + seq ; x = LN(lin) ; xp_{f,b} = x@Wk_{f,b} + bias0
__global__ __launch_bounds__(256) void layer_front(
    const float* __restrict__ xs_l,   // [4096][768]
    const float* __restrict__ W_lin,  // [768][64]
    const float* __restrict__ b_lin,  // [64]
    const float* __restrict__ ln_g,   // [64]
    const float* __restrict__ ln_b,   // [64]
    const float* __restrict__ Wk_f,   // [64][96]
    const float* __restrict__ b_f0,   // [2][96] (row 0 used)
    const float* __restrict__ Wk_b,   // [64][96]
    const float* __restrict__ b_b0,   // [2][96] (row 0 used)
    const float* __restrict__ seq,    // [4096][64]
    float* __restrict__ xp_f,         // [4096][96]
    float* __restrict__ xp_b)         // [4096][96]
{
    __shared__ float sA[ROWS][BK + 4];   // xs tile (padded vs 4-way bank conflict)
    __shared__ float sW[BK][GG];         // W_lin tile
    __shared__ float sX[ROWS][GG + 4];   // normalized x

    const int t = threadIdx.x;
    const int row0 = blockIdx.x * ROWS;

    // phase1 mapping: each thread: 1 row (r1), 4 cols (c1..c1+3); 16-lane group = one row
    const int r1 = t >> 4;
    const int c1 = (t & 15) << 2;

    float acc0 = 0.f, acc1 = 0.f, acc2 = 0.f, acc3 = 0.f;

    for (int kt = 0; kt < HID; kt += BK) {
        for (int i = t; i < ROWS * BK / 4; i += 256) {
            int rr = i >> 5;
            int kk = (i & 31) << 2;
            *(float4*)&sA[rr][kk] =
                *(const float4*)&xs_l[(size_t)(row0 + rr) * HID + kt + kk];
        }
        for (int i = t; i < BK * GG / 4; i += 256) {
            int kk = i >> 4;
            int cc = (i & 15) << 2;
            *(float4*)&sW[kk][cc] = *(const float4*)&W_lin[(size_t)(kt + kk) * GG + cc];
        }
        __syncthreads();
        #pragma unroll
        for (int k4 = 0; k4 < BK; k4 += 4) {
            float4 a  = *(const float4*)&sA[r1][k4];
            float4 w0 = *(const float4*)&sW[k4 + 0][c1];
            float4 w1 = *(const float4*)&sW[k4 + 1][c1];
            float4 w2 = *(const float4*)&sW[k4 + 2][c1];
            float4 w3 = *(const float4*)&sW[k4 + 3][c1];
            acc0 += a.x * w0.x + a.y * w1.x + a.z * w2.x + a.w * w3.x;
            acc1 += a.x * w0.y + a.y * w1.y + a.z * w2.y + a.w * w3.y;
            acc2 += a.x * w0.z + a.y * w1.z + a.z * w2.z + a.w * w3.z;
            acc3 += a.x * w0.w + a.y * w1.w + a.z * w2.w + a.w * w3.w;
        }
        __syncthreads();
    }

    // bias + residual + layernorm over the 64-wide row (held across a 16-lane group)
    {
        const float4 sq = *(const float4*)&seq[(size_t)(row0 + r1) * GG + c1];
        const float4 bl = *(const float4*)&b_lin[c1];
        float v0 = acc0 + bl.x + sq.x;
        float v1 = acc1 + bl.y + sq.y;
        float v2 = acc2 + bl.z + sq.z;
        float v3 = acc3 + bl.w + sq.w;
        float s = v0 + v1 + v2 + v3;
        #pragma unroll
        for (int off = 1; off < 16; off <<= 1) s += __shfl_xor(s, off);
        float mean = s * (1.0f / 64.0f);
        float d0 = v0 - mean, d1 = v1 - mean, d2 = v2 - mean, d3 = v3 - mean;
        float q = d0 * d0 + d1 * d1 + d2 * d2 + d3 * d3;
        #pragma unroll
        for (int off = 1; off < 16; off <<= 1) q += __shfl_xor(q, off);
        float rstd = rsqrtf(q * (1.0f / 64.0f) + LN_EPS);
        const float4 gm = *(const float4*)&ln_g[c1];
        const float4 bt = *(const float4*)&ln_b[c1];
        sX[r1][c1 + 0] = d0 * rstd * gm.x + bt.x;
        sX[r1][c1 + 1] = d1 * rstd * gm.y + bt.y;
        sX[r1][c1 + 2] = d2 * rstd * gm.z + bt.z;
        sX[r1][c1 + 3] = d3 * rstd * gm.w + bt.w;
    }
    __syncthreads();

    // phase2: xp = x @ Wk + bias0 ; thread: row r2 = t&15, 12 cols c0 = (t>>4)*12
    {
        const int r2 = t & 15;
        const int cg = t >> 4;
        const int c0 = cg * 12;                 // 0..180 over [xp_f | xp_b]
        const bool fwd = (c0 < TU);
        const float* Wk = fwd ? Wk_f : Wk_b;
        const float* bi = fwd ? b_f0 : b_b0;
        const int cc = fwd ? c0 : (c0 - TU);

        float a2[12];
        #pragma unroll
        for (int m = 0; m < 12; ++m) a2[m] = bi[cc + m];

        #pragma unroll 8
        for (int k = 0; k < GG; ++k) {
            float xv = sX[r2][k];
            const float4 wA = *(const float4*)&Wk[k * TU + cc];
            const float4 wB = *(const float4*)&Wk[k * TU + cc + 4];
            const float4 wC = *(const float4*)&Wk[k * TU + cc + 8];
            a2[0] += xv * wA.x;  a2[1] += xv * wA.y;  a2[2]  += xv * wA.z;  a2[3]  += xv * wA.w;
            a2[4] += xv * wB.x;  a2[5] += xv * wB.y;  a2[6]  += xv * wB.z;  a2[7]  += xv * wB.w;
            a2[8] += xv * wC.x;  a2[9] += xv * wC.y;  a2[10] += xv * wC.z;  a2[11] += xv * wC.w;
        }
        float* dst = fwd ? xp_f : xp_b;
        size_t base = (size_t)(row0 + r2) * TU + cc;
        *(float4*)&dst[base + 0] = make_float4(a2[0], a2[1], a2[2], a2[3]);
        *(float4*)&dst[base + 4] = make_float4(a2[4], a2[5], a2[6], a2[7]);
        *(float4*)&dst[base + 8] = make_float4(a2[8], a2[9], a2[10], a2[11]);
    }
}

// One wave per (direction, batch-pair). Wr + h-row in registers; LDS broadcast per step.
__global__ __launch_bounds__(64) void gru_scan(
    const float* __restrict__ xp_f, const float* __restrict__ xp_b,
    const float* __restrict__ Wr_f, const float* __restrict__ b_f,
    const float* __restrict__ Wr_b, const float* __restrict__ b_b,
    float* __restrict__ seq, float* __restrict__ h1, float* __restrict__ h2)
{
    const int w = blockIdx.x;
    const int dir = w >> 4;           // 0 = fwd, 1 = bwd
    const int pr = w & 15;            // batch pair
    const int lane = threadIdx.x;
    const int bl = lane >> 5;         // batch within pair
    const int u = lane & 31;          // GRU unit
    const int b = pr * 2 + bl;

    const float* xp = dir ? xp_b : xp_f;
    const float* Wr = dir ? Wr_b : Wr_f;
    const float* rb = (dir ? b_b : b_f) + TU;   // recurrent bias row
    float* hst = dir ? h2 : h1;

    float wz[NU], wr[NU], wh[NU];
    #pragma unroll
    for (int j = 0; j < NU; ++j) {
        wz[j] = Wr[j * TU + u];
        wr[j] = Wr[j * TU + NU + u];
        wh[j] = Wr[j * TU + 2 * NU + u];
    }
    float hreg[NU];
    #pragma unroll
    for (int j = 0; j < NU; ++j) hreg[j] = hst[b * NU + j];
    float h_own = hst[b * NU + u];

    const float rbz = rb[u], rbr = rb[NU + u], rbh = rb[2 * NU + u];

    __shared__ float buf[2][64];

    int sx = dir ? (SEQ - 1) : 0;
    const float* xr0 = xp + ((size_t)b * SEQ + sx) * TU;
    float xz = xr0[u], xr_ = xr0[NU + u], xh = xr0[2 * NU + u];

    for (int s = 0; s < SEQ; ++s) {
        // prefetch next step's xp (hides global latency under the FMAs)
        float nz = 0.f, nr = 0.f, nh = 0.f;
        if (s + 1 < SEQ) {
            int sxn = dir ? (SEQ - 2 - s) : (s + 1);
            const float* xrn = xp + ((size_t)b * SEQ + sxn) * TU;
            nz = xrn[u]; nr = xrn[NU + u]; nh = xrn[2 * NU + u];
        }

        float rz0 = 0.f, rz1 = 0.f, rr0 = 0.f, rr1 = 0.f, rh0 = 0.f, rh1 = 0.f;
        #pragma unroll
        for (int j = 0; j < NU; j += 2) {
            rz0 += hreg[j] * wz[j];     rz1 += hreg[j + 1] * wz[j + 1];
            rr0 += hreg[j] * wr[j];     rr1 += hreg[j + 1] * wr[j + 1];
            rh0 += hreg[j] * wh[j];     rh1 += hreg[j + 1] * wh[j + 1];
        }
        float rz  = rbz + rz0 + rz1;
        float rrv = rbr + rr0 + rr1;
        float rh  = rbh + rh0 + rh1;

        float z  = sigmoidf_(xz + rz);
        float r  = sigmoidf_(xr_ + rrv);
        float hh = tanhf_(xh + r * rh);
        float hn = z * h_own + (1.0f - z) * hh;

        buf[s & 1][lane] = hn;
        __syncthreads();
        #pragma unroll
        for (int q = 0; q < 8; ++q) {
            float4 v = *(const float4*)&buf[s & 1][bl * 32 + q * 4];
            hreg[q * 4 + 0] = v.x; hreg[q * 4 + 1] = v.y;
            hreg[q * 4 + 2] = v.z; hreg[q * 4 + 3] = v.w;
        }

        seq[((size_t)b * SEQ + sx) * GG + dir * NU + u] = hn;
        h_own = hn;
        xz = nz; xr_ = nr; xh = nh;
        sx = dir ? (sx - 1) : (sx + 1);
    }
    hst[b * NU + u] = h_own;
}

__global__ __launch_bounds__(64) void classifier(
    const float* __restrict__ h1, const float* __restrict__ h2,
    const float* __restrict__ W_cls, const float* __restrict__ b_cls,
    float* __restrict__ out)
{
    const int lane = threadIdx.x;   // lane = b*2 + n
    const int b = lane >> 1;
    const int n = lane & 1;
    float acc = b_cls[n];
    #pragma unroll
    for (int j = 0; j < NU; ++j) {
        acc += h1[b * NU + j] * W_cls[(2 * j) * 2 + n];       // hcat[2j]   = h1[j]
        acc += h2[b * NU + j] * W_cls[(2 * j + 1) * 2 + n];   // hcat[2j+1] = h2[j]
    }
    float other = __shfl_xor(acc, 1);
    float m = fmaxf(acc, other);
    float e = __expf(acc - m);
    float eo = __expf(other - m);
    out[lane] = e / (e + eo);
}

extern "C" void kernel_launch(void* const* d_in, const int* in_sizes, int n_in,
                              void* d_out, int out_size, void* d_ws, size_t ws_size,
                              hipStream_t stream) {
    const float* xs    = (const float*)d_in[0];
    const float* W_lin = (const float*)d_in[1];
    const float* b_lin = (const float*)d_in[2];
    const float* ln_g  = (const float*)d_in[3];
    const float* ln_b  = (const float*)d_in[4];
    const float* Wk_f  = (const float*)d_in[5];
    const float* Wr_f  = (const float*)d_in[6];
    const float* b_f   = (const float*)d_in[7];
    const float* Wk_b  = (const float*)d_in[8];
    const float* Wr_b  = (const float*)d_in[9];
    const float* b_b   = (const float*)d_in[10];
    const float* W_cls = (const float*)d_in[11];
    const float* b_cls = (const float*)d_in[12];
    float* out = (float*)d_out;

    char* ws = (char*)d_ws;
    float* seq  = (float*)(ws);                               // 4096*64 f32 = 1 MB
    float* xp_f = (float*)(ws + 1048576);                     // 4096*96 f32
    float* xp_b = (float*)(ws + 1048576 + 1572864);           // 4096*96 f32
    float* h1   = (float*)(ws + 1048576 + 2 * 1572864);       // 32*32 f32
    float* h2   = h1 + BATCH * NU;

    hipMemsetAsync(seq, 0, (size_t)NROWS * GG * sizeof(float), stream);
    hipMemsetAsync(h1, 0, (size_t)2 * BATCH * NU * sizeof(float), stream);

    for (int l = 0; l < NLAYERS; ++l) {
        layer_front<<<NROWS / ROWS, 256, 0, stream>>>(
            xs + (size_t)l * NROWS * HID, W_lin, b_lin, ln_g, ln_b,
            Wk_f, b_f, Wk_b, b_b, seq, xp_f, xp_b);
        gru_scan<<<32, 64, 0, stream>>>(xp_f, xp_b, Wr_f, b_f, Wr_b, b_b, seq, h1, h2);
    }
    classifier<<<1, 64, 0, stream>>>(h1, h2, W_cls, b_cls, out);
}